// Round 5
// baseline (85.873 us; speedup 1.0000x reference)
//
#include <hip/hip_runtime.h>
#include <math.h>
#include <float.h>

#define B_ 64
#define T_ 100
#define N_ 20000
#define NQ (B_ * T_)              // 6400 queries
#define NCHUNKS 250
#define CHUNK (N_ / NCHUNKS)      // 80 points per chunk
#define CPAIRS (CHUNK / 2)        // 40 pairs per chunk
#define GROUPS (CPAIRS / 2)       // 20 groups (4 points) per chunk
#define QG 640                    // queries per block (amortizes LDS broadcast)
#define NQG (NQ / QG)             // 10
#define QPT 10                    // queries per thread
#define K1_THREADS 64             // one wave per block

typedef float f2 __attribute__((ext_vector_type(2)));
typedef float f4 __attribute__((ext_vector_type(4)));
typedef unsigned long long u64;

// ws layout: keys u64[NQ] (51.2 KB), init to 0xFF..F by hipMemsetAsync.
// packed key = (sortable(e) << 32) | point_idx -> min e, ties -> lowest idx.
#define KEYS_OFF 0

// Map f32 -> u32 preserving < order for all finite values (incl. negatives).
__device__ __forceinline__ unsigned int f32_sortable(float f) {
    unsigned int u = __float_as_uint(f);
    return ((int)u >= 0) ? (u | 0x80000000u) : ~u;
}

// ---------------------------------------------------------------------------
// Kernel 1: global-frame partial 1-NN. Block = (query-group of 640, chunk of
// 80 points). Rigid transforms preserve distance: |w - R^T(g-t)| = |(Rw+t)-g|,
// so the NN search runs in the global frame (batch-independent point data).
// 64 threads x 10 queries each: every staged group of 4 points (4 LDS reads)
// is amortized over 40 evals -> LDS pipe drops from 9.8us to 3.9us total, and
// 10 independent query chains per thread give ILP to hide ds_read latency.
// ---------------------------------------------------------------------------
__global__ __launch_bounds__(K1_THREADS) void k1_nn(
    const float* __restrict__ poses,      // [B,4,4]
    const float* __restrict__ wpts,       // [B,T,3]
    const float* __restrict__ boundary,   // [4,N]
    u64* __restrict__ keys)               // [NQ]
{
    __shared__ f4 sh[GROUPS][4];          // [g][0..3]: {a0,b0,a1,b1}
                                          // a={-2x0,-2x1,-2y0,-2y1}
                                          // b={-2z0,-2z1, p2_0, p2_1}
    __shared__ float sposes[B_ * 16];     // all poses, 4 KB

    const int bx   = blockIdx.x;
    const int qg   = bx / NCHUNKS;
    const int c    = bx - qg * NCHUNKS;
    const int base = c * CHUNK;
    const int tid  = threadIdx.x;

    // ---- stage all poses into LDS (coalesced f4 copy, 4 per thread) ----
    {
        const f4* pg  = (const f4*)poses;
        f4*       sp4 = (f4*)sposes;
#pragma unroll
        for (int j = 0; j < 4; ++j)
            sp4[j * 64 + tid] = pg[j * 64 + tid];
    }

    // ---- stage chunk: pair p -> group p>>1, slot (p&1)*2 ----
    if (tid < CPAIRS) {
        const int n0 = base + 2 * tid;
        const float x0 = boundary[n0],          x1 = boundary[n0 + 1];
        const float y0 = boundary[N_ + n0],     y1 = boundary[N_ + n0 + 1];
        const float z0 = boundary[2 * N_ + n0], z1 = boundary[2 * N_ + n0 + 1];
        f4 a = { -2.f * x0, -2.f * x1, -2.f * y0, -2.f * y1 };
        f4 b = { -2.f * z0, -2.f * z1,
                 x0 * x0 + y0 * y0 + z0 * z0,
                 x1 * x1 + y1 * y1 + z1 * z1 };
        sh[tid >> 1][(tid & 1) * 2 + 0] = a;
        sh[tid >> 1][(tid & 1) * 2 + 1] = b;
    }
    __syncthreads();

    // ---- per-thread queries: global waypoint q = R w + t ----
    float qx[QPT], qy[QPT], qz[QPT];
#pragma unroll
    for (int k = 0; k < QPT; ++k) {
        const int i = qg * QG + k * 64 + tid;
        const int b = i / T_;
        const float* P = sposes + b * 16;
        const float* W = wpts + i * 3;
        const float wx = W[0], wy = W[1], wz = W[2];
        qx[k] = P[0] * wx + P[1] * wy + P[2]  * wz + P[3];
        qy[k] = P[4] * wx + P[5] * wy + P[6]  * wz + P[7];
        qz[k] = P[8] * wx + P[9] * wy + P[10] * wz + P[11];
    }

    float beste[QPT];
    int   bg[QPT];
#pragma unroll
    for (int k = 0; k < QPT; ++k) { beste[k] = FLT_MAX; bg[k] = 0; }

#pragma unroll 4
    for (int g = 0; g < GROUPS; ++g) {
        const f4 A0 = sh[g][0], B0 = sh[g][1];
        const f4 A1 = sh[g][2], B1 = sh[g][3];
        const f2 mx0 = { A0.x, A0.y }, my0 = { A0.z, A0.w };
        const f2 mz0 = { B0.x, B0.y }, p20 = { B0.z, B0.w };
        const f2 mx1 = { A1.x, A1.y }, my1 = { A1.z, A1.w };
        const f2 mz1 = { B1.x, B1.y }, p21 = { B1.z, B1.w };

#pragma unroll
        for (int k = 0; k < QPT; ++k) {
            const f2 vx = { qx[k], qx[k] };
            const f2 vy = { qy[k], qy[k] };
            const f2 vz = { qz[k], qz[k] };
            // e = p2 - 2 q.g  (3 packed FMAs per 2 points)
            f2 eA = __builtin_elementwise_fma(mx0, vx,
                    __builtin_elementwise_fma(my0, vy,
                    __builtin_elementwise_fma(mz0, vz, p20)));
            f2 eB = __builtin_elementwise_fma(mx1, vx,
                    __builtin_elementwise_fma(my1, vy,
                    __builtin_elementwise_fma(mz1, vz, p21)));
            f2 m2 = __builtin_elementwise_min(eA, eB);
            float m = fminf(m2.x, m2.y);
            const bool cc = m < beste[k];
            beste[k] = cc ? m : beste[k];
            bg[k]    = cc ? g : bg[k];
        }
    }

    // ---- resolve exact index inside each winning group ----
    // Divergent LDS reads, once per query. Same IEEE fma sequence as the main
    // loop -> bitwise-identical e values -> the == test finds the winner.
#pragma unroll
    for (int k = 0; k < QPT; ++k) {
        const int g = bg[k];
        const f4 A0 = sh[g][0], B0 = sh[g][1];
        const f4 A1 = sh[g][2], B1 = sh[g][3];
        const f2 mx0 = { A0.x, A0.y }, my0 = { A0.z, A0.w };
        const f2 mz0 = { B0.x, B0.y }, p20 = { B0.z, B0.w };
        const f2 mx1 = { A1.x, A1.y }, my1 = { A1.z, A1.w };
        const f2 mz1 = { B1.x, B1.y }, p21 = { B1.z, B1.w };
        const f2 vx = { qx[k], qx[k] };
        const f2 vy = { qy[k], qy[k] };
        const f2 vz = { qz[k], qz[k] };
        f2 eA = __builtin_elementwise_fma(mx0, vx,
                __builtin_elementwise_fma(my0, vy,
                __builtin_elementwise_fma(mz0, vz, p20)));
        f2 eB = __builtin_elementwise_fma(mx1, vx,
                __builtin_elementwise_fma(my1, vy,
                __builtin_elementwise_fma(mz1, vz, p21)));
        const int loc = base + 4 * g;
        const int li = (eA.x == beste[k]) ? loc
                     : (eA.y == beste[k]) ? loc + 1
                     : (eB.x == beste[k]) ? loc + 2 : loc + 3;
        const u64 key = ((u64)f32_sortable(beste[k]) << 32) | (unsigned)li;
        const int i = qg * QG + k * 64 + tid;
        atomicMin(&keys[i], key);
    }
}

// ---------------------------------------------------------------------------
// Kernel 2: per query, unpack winning index, global-frame epilogue:
// dots = (q - g) . n  (rotation-invariant == reference's local-frame dot),
// ExpRelu, block-reduce, atomicAdd into out (zeroed by hipMemsetAsync).
// ---------------------------------------------------------------------------
__global__ __launch_bounds__(256) void k2_epilogue(
    const float* __restrict__ poses,
    const float* __restrict__ wpts,
    const float* __restrict__ boundary,   // [4,N]
    const float* __restrict__ bnorm,      // [3,N]
    const u64* __restrict__ keys,
    float* __restrict__ out)
{
    const int tid = threadIdx.x;
    const int i = blockIdx.x * 256 + tid;     // grid = 25 -> i in [0,6400)

    const int bi = (int)(unsigned)(keys[i] & 0xFFFFFFFFull);

    const int b = i / T_;
    const float* P = poses + b * 16;
    const float* W = wpts + i * 3;
    const float wx = W[0], wy = W[1], wz = W[2];
    const float qx = P[0] * wx + P[1] * wy + P[2]  * wz + P[3];
    const float qy = P[4] * wx + P[5] * wy + P[6]  * wz + P[7];
    const float qz = P[8] * wx + P[9] * wy + P[10] * wz + P[11];

    const float gx = boundary[bi], gy = boundary[N_ + bi], gz = boundary[2 * N_ + bi];
    const float nx = bnorm[bi],    ny = bnorm[N_ + bi],    nz = bnorm[2 * N_ + bi];

    const float dots = (qx - gx) * nx + (qy - gy) * ny + (qz - gz) * nz;
    // ExpRelu: alpha=1, beta=0.5; pre-scaled for the final mean
    float val = (dots > 0.0f) ? (dots + 1.0f) : expf(0.5f * dots);
    val *= (1.0f / (float)NQ);

    __shared__ float red[256];
    red[tid] = val;
    __syncthreads();
#pragma unroll
    for (int s = 128; s > 0; s >>= 1) {
        if (tid < s) red[tid] += red[tid + s];
        __syncthreads();
    }
    if (tid == 0) atomicAdd(out, red[0]);
}

extern "C" void kernel_launch(void* const* d_in, const int* in_sizes, int n_in,
                              void* d_out, int out_size, void* d_ws, size_t ws_size,
                              hipStream_t stream) {
    const float* poses    = (const float*)d_in[0];
    const float* wpts     = (const float*)d_in[1];
    const float* boundary = (const float*)d_in[2];
    const float* bnorm    = (const float*)d_in[3];
    float* out = (float*)d_out;

    u64* keys = (u64*)((char*)d_ws + KEYS_OFF);

    // keys -> all-ones (u64 max, loses to any real key); out -> 0
    hipMemsetAsync(keys, 0xFF, NQ * sizeof(u64), stream);
    hipMemsetAsync(out, 0, sizeof(float), stream);

    k1_nn<<<NQG * NCHUNKS, K1_THREADS, 0, stream>>>(
        poses, wpts, boundary, keys);
    k2_epilogue<<<NQ / 256, 256, 0, stream>>>(
        poses, wpts, boundary, bnorm, keys, out);
}